// Round 2
// baseline (9274.343 us; speedup 1.0000x reference)
//
#include <hip/hip_runtime.h>
#include <stdint.h>
#include <stddef.h>

// Problem constants (match reference)
#define BB 128
#define SS 128
#define EE 256
#define DD 512
#define KK 16
#define LL 1906   // 1 + 127*15
#define RR 2033   // 1 + 127*16
#define NSTEP 127

// ---------------- JAX threefry2x32 (bit-exact) ----------------
static __device__ __forceinline__ uint32_t rotl32(uint32_t v, int r) {
  return (v << r) | (v >> (32 - r));
}

static __device__ __forceinline__ void tf2x32(uint32_t k0, uint32_t k1,
                                              uint32_t x0, uint32_t x1,
                                              uint32_t &o0, uint32_t &o1) {
  uint32_t ks2 = k0 ^ k1 ^ 0x1BD11BDAu;
  x0 += k0; x1 += k1;
#define TFR(r) { x0 += x1; x1 = rotl32(x1, (r)); x1 ^= x0; }
  TFR(13) TFR(15) TFR(26) TFR(6)
  x0 += k1;  x1 += ks2 + 1u;
  TFR(17) TFR(29) TFR(16) TFR(24)
  x0 += ks2; x1 += k0 + 2u;
  TFR(13) TFR(15) TFR(26) TFR(6)
  x0 += k0;  x1 += k1 + 3u;
  TFR(17) TFR(29) TFR(16) TFR(24)
  x0 += k1;  x1 += ks2 + 4u;
  TFR(13) TFR(15) TFR(26) TFR(6)
  x0 += ks2; x1 += k0 + 5u;
#undef TFR
  o0 = x0; o1 = x1;
}

// jax uniform->gumbel for one 32-bit word (minval=f32 tiny, maxval=1)
static __device__ __forceinline__ float jax_gumbel(uint32_t bits) {
  float f = __uint_as_float((bits >> 9) | 0x3F800000u) - 1.0f;
  float u = fmaxf(f, 1.17549435e-38f);  // (1-tiny)==1 in f32, so u = max(f, tiny)
  return -logf(-logf(u));
}

// ---------------- main persistent kernel: one block per batch row ----------------
__global__ __launch_bounds__(1024) void rnn_gen_kernel(
    const int*   __restrict__ marker_data,   // (B,S) int32
    const float* __restrict__ time_data,     // (B,S)
    const float* __restrict__ mask_data,     // (B,S)
    const float* __restrict__ embedding,     // (50000,E)
    const int*   __restrict__ neighbor_list, // (50000,K) int32
    const float* __restrict__ neighbor_prob, // (50000,K)
    const float* __restrict__ W_te,          // (1,E)
    const float* __restrict__ b_te,          // (E)
    const float* __restrict__ W_el,          // (E,D)
    const float* __restrict__ b_el,          // (D)
    const float* __restrict__ W_ih,          // (D,D)
    const float* __restrict__ b_ih,          // (D)
    const float* __restrict__ W_hh,          // (D,D)
    const float* __restrict__ b_hh,          // (D)
    const float* __restrict__ W_time,        // (D,1)
    const float* __restrict__ b_time,        // (1)
    const float* __restrict__ W_mk,          // (E+D,1)
    const float* __restrict__ b_mk,          // (1)
    float* __restrict__ out)                 // 5 x (B,S) f32, concat
{
  __shared__ float  s_prob[LL];
  __shared__ int    s_cand[LL];
  __shared__ float  s_nrec[RR];
  __shared__ float  s_x[DD];
  __shared__ float  s_h[DD];
  __shared__ float  s_vec[EE];
  __shared__ double s_dbuf[1024];
  __shared__ float  s_score[KK];
  __shared__ float  s_red_z[16];
  __shared__ int    s_red_i[16];
  __shared__ int    s_neigh[KK];
  __shared__ float  s_last_t;
  __shared__ int    s_last_m;
  __shared__ int    s_chosen;
  __shared__ float  s_newt;
  __shared__ uint32_t s_k0, s_k1;

  const int b   = blockIdx.x;
  const int tid = threadIdx.x;

  // ---- init carry + col 0 outputs
  for (int i = tid; i < LL; i += 1024) { s_prob[i] = 0.0f; s_cand[i] = 0; }
  for (int i = tid; i < RR; i += 1024) s_nrec[i] = 1.0f;
  if (tid < DD) s_h[tid] = 0.0f;
  if (tid == 0) {
    int   m0 = marker_data[b * SS];
    float t0 = time_data[b * SS];
    s_cand[0] = m0; s_prob[0] = 1.0f;
    s_last_m = m0; s_last_t = t0; s_chosen = 0;
    out[0 * BB * SS + b * SS + 0] = (float)m0;
    out[1 * BB * SS + b * SS + 0] = t0;
    out[2 * BB * SS + b * SS + 0] = mask_data[b * SS];
    out[3 * BB * SS + b * SS + 0] = 1.0f;
    out[4 * BB * SS + b * SS + 0] = 1.0f;
  }
  __syncthreads();

  for (int t = 0; t < NSTEP; ++t) {
    const int   m  = s_last_m;
    const float lt = s_last_t;

    // ---- step key (thread 0): partitionable threefry split —
    //      keys[t] = full threefry block with 64-bit counter (hi=0, lo=t)
    if (tid == 0) {
      uint32_t o0, o1;
      tf2x32(0u, 42u, 0u, (uint32_t)t, o0, o1);
      s_k0 = o0; s_k1 = o1;
    }
    if (tid < EE) {
      // time_emb = last_t*W_te + b_te ; vec = emb[m] + 0.1f*time_emb  (no FMA contraction)
      float te = __fadd_rn(__fmul_rn(lt, W_te[tid]), b_te[tid]);
      s_vec[tid] = __fadd_rn(embedding[(size_t)m * EE + tid], __fmul_rn(0.1f, te));
    }
    if (tid >= 256 && tid < 256 + KK) {
      int k = tid - 256;
      int nb = neighbor_list[(size_t)m * KK + k];
      s_neigh[k] = nb;
      s_nrec[1 + t * KK + k] = neighbor_prob[(size_t)m * KK + k];
      if (k >= 1) s_cand[1 + t * (KK - 1) + (k - 1)] = nb;
    }
    __syncthreads();

    // ---- x = leaky(vec @ W_el + b_el) ; K=256 split across thread halves, f64 acc
    {
      const int j    = tid & (DD - 1);
      const int e0   = (tid >> 9) << 7;   // 0 or 128
      const float *col = W_el + j;
      double a0 = 0.0, a1 = 0.0;
#pragma unroll 8
      for (int e = 0; e < 128; e += 2) {
        a0 = fma((double)s_vec[e0 + e],     (double)col[(size_t)(e0 + e) * DD],     a0);
        a1 = fma((double)s_vec[e0 + e + 1], (double)col[(size_t)(e0 + e + 1) * DD], a1);
      }
      s_dbuf[tid] = a0 + a1;
    }
    __syncthreads();
    if (tid < DD) {
      float dot = (float)(s_dbuf[tid] + s_dbuf[tid + DD]);   // rounds once (like XLA dot)
      float z = __fadd_rn(dot, b_el[tid]);
      s_x[tid] = (z >= 0.0f) ? z : __fmul_rn(0.01f, z);
    }
    __syncthreads();

    // ---- h = tanh(((x@W_ih + b_ih) + h@W_hh) + b_hh)
    {
      const int  j   = tid & (DD - 1);
      const bool ihp = (tid < DD);
      const float *Wcol = (ihp ? W_ih : W_hh) + j;
      const float *av   = ihp ? s_x : s_h;
      double a0 = 0.0, a1 = 0.0, a2 = 0.0, a3 = 0.0;
#pragma unroll 4
      for (int i = 0; i < DD; i += 4) {
        a0 = fma((double)av[i + 0], (double)Wcol[(size_t)(i + 0) * DD], a0);
        a1 = fma((double)av[i + 1], (double)Wcol[(size_t)(i + 1) * DD], a1);
        a2 = fma((double)av[i + 2], (double)Wcol[(size_t)(i + 2) * DD], a2);
        a3 = fma((double)av[i + 3], (double)Wcol[(size_t)(i + 3) * DD], a3);
      }
      s_dbuf[tid] = (a0 + a1) + (a2 + a3);
    }
    __syncthreads();
    if (tid < DD) {
      float p = __fadd_rn(__fadd_rn(__fadd_rn((float)s_dbuf[tid], b_ih[tid]),
                                    (float)s_dbuf[tid + DD]),
                          b_hh[tid]);
      s_h[tid] = (float)tanh((double)p);
    }
    __syncthreads();

    // ---- reductions: h.W_time (dbuf[0]) and h.W_mk[E:] (dbuf[512]), f64 (order-free)
    if (tid < DD) {
      double hv = (double)s_h[tid];
      s_dbuf[tid]      = hv * (double)W_time[tid];
      s_dbuf[tid + DD] = hv * (double)W_mk[EE + tid];
    }
    __syncthreads();
    for (int stw = 256; stw > 0; stw >>= 1) {
      if (tid < stw) s_dbuf[tid] += s_dbuf[tid + stw];
      else if (tid >= DD && tid < DD + stw) s_dbuf[tid] += s_dbuf[tid + stw];
      __syncthreads();
    }

    // ---- new_t (thread 0) + scores (tid<512: 16 k-groups of 32 lanes)
    if (tid == 0) {
      float td = __fadd_rn((float)s_dbuf[0], b_time[0]);
      // jax softplus = logaddexp(x,0) = max(x,0) + log1p(exp(-|x|))
      float sp = __fadd_rn(fmaxf(td, 0.0f), log1pf(expf(-fabsf(td))));
      s_newt = __fadd_rn(s_last_t, sp);
    }
    if (tid < 512) {
      int k = tid >> 5, lane = tid & 31;
      const float *erow = embedding + (size_t)s_neigh[k] * EE;
      double acc = 0.0;
#pragma unroll
      for (int mb = 0; mb < 8; ++mb) {
        int e = lane + (mb << 5);
        acc = fma((double)erow[e], (double)W_mk[e], acc);
      }
      for (int off = 16; off > 0; off >>= 1) acc += __shfl_down(acc, off, 32);
      if (lane == 0)
        s_score[k] = __fadd_rn((float)(acc + s_dbuf[DD]), b_mk[0]);  // rounds 768-dot once
    }
    __syncthreads();

    // ---- softmax + prob bookkeeping (thread 0, f32 stepwise like jax)
    if (tid == 0) {
      float mx = s_score[0];
      for (int k = 1; k < KK; ++k) mx = fmaxf(mx, s_score[k]);
      float ee[KK]; float ssum = 0.0f;
      for (int k = 0; k < KK; ++k) {
        ee[k] = expf(__fsub_rn(s_score[k], mx));
        ssum = __fadd_rn(ssum, ee[k]);
      }
      float cp = s_prob[s_chosen];
      for (int k = 0; k < KK; ++k) {
        float mp = __fdiv_rn(ee[k], ssum);
        float at = __fmul_rn(cp, mp);
        if (k == 0) s_prob[s_chosen] = at;
        else        s_prob[1 + t * (KK - 1) + (k - 1)] = at;
      }
    }
    __syncthreads();

    // ---- categorical sampling: argmax over logits + gumbel.
    //      Partitionable threefry random_bits: word[i] = o0 ^ o1 of
    //      tf2x32(key, hi=0, lo=i), flat i = b*LL + l (row-major).
    //      Inactive entries (l >= active) have logit -1e30 and cannot win.
    const int active = 16 + 15 * t;
    const uint32_t kk0 = s_k0, kk1 = s_k1;
    float bz = -3.0e38f;
    int   bi = 0x7FFFFFFF;
    for (int l = tid; l < active; l += 1024) {
      uint32_t i = (uint32_t)(b * LL + l);
      uint32_t o0, o1;
      tf2x32(kk0, kk1, 0u, i, o0, o1);
      float g  = jax_gumbel(o0 ^ o1);
      float pr = s_prob[l];
      float z  = (pr > 0.0f) ? __fadd_rn(logf(fmaxf(pr, 1e-38f)), g)
                             : __fadd_rn(-1e30f, g);
      if (z > bz) { bz = z; bi = l; }   // l ascending => strict > keeps first index
    }
    for (int off = 32; off > 0; off >>= 1) {
      float oz = __shfl_down(bz, off);
      int   oi = __shfl_down(bi, off);
      if (oz > bz || (oz == bz && oi < bi)) { bz = oz; bi = oi; }
    }
    if ((tid & 63) == 0) { s_red_z[tid >> 6] = bz; s_red_i[tid >> 6] = bi; }
    __syncthreads();

    // ---- finalize step (thread 0): pick winner, outputs, carry update
    if (tid == 0) {
      float z0 = s_red_z[0]; int i0 = s_red_i[0];
      for (int w = 1; w < 16; ++w) {
        if (s_red_z[w] > z0 || (s_red_z[w] == z0 && s_red_i[w] < i0)) {
          z0 = s_red_z[w]; i0 = s_red_i[w];
        }
      }
      int   nm  = s_cand[i0];
      float np_ = s_nrec[i0];
      float sp_ = s_prob[i0];
      float nt  = s_newt;
      out[0 * BB * SS + b * SS + (t + 1)] = (float)nm;
      out[1 * BB * SS + b * SS + (t + 1)] = nt;
      out[2 * BB * SS + b * SS + (t + 1)] = (nt < 1000.0f) ? 1.0f : 0.0f;
      out[3 * BB * SS + b * SS + (t + 1)] = np_;
      out[4 * BB * SS + b * SS + (t + 1)] = sp_;
      s_chosen = i0; s_last_m = nm; s_last_t = nt;
    }
    __syncthreads();
  }
}

extern "C" void kernel_launch(void* const* d_in, const int* in_sizes, int n_in,
                              void* d_out, int out_size, void* d_ws, size_t ws_size,
                              hipStream_t stream) {
  (void)in_sizes; (void)n_in; (void)out_size; (void)d_ws; (void)ws_size;
  const int*   marker_data   = (const int*)  d_in[0];
  const float* time_data     = (const float*)d_in[1];
  const float* mask_data     = (const float*)d_in[2];
  const float* embedding     = (const float*)d_in[3];
  const int*   neighbor_list = (const int*)  d_in[4];
  const float* neighbor_prob = (const float*)d_in[5];
  const float* W_te   = (const float*)d_in[6];
  const float* b_te   = (const float*)d_in[7];
  const float* W_el   = (const float*)d_in[8];
  const float* b_el   = (const float*)d_in[9];
  const float* W_ih   = (const float*)d_in[10];
  const float* b_ih   = (const float*)d_in[11];
  const float* W_hh   = (const float*)d_in[12];
  const float* b_hh   = (const float*)d_in[13];
  const float* W_time = (const float*)d_in[14];
  const float* b_time = (const float*)d_in[15];
  const float* W_mk   = (const float*)d_in[16];
  const float* b_mk   = (const float*)d_in[17];
  float* out = (float*)d_out;

  hipLaunchKernelGGL(rnn_gen_kernel, dim3(BB), dim3(1024), 0, stream,
                     marker_data, time_data, mask_data, embedding,
                     neighbor_list, neighbor_prob,
                     W_te, b_te, W_el, b_el, W_ih, b_ih, W_hh, b_hh,
                     W_time, b_time, W_mk, b_mk, out);
}

// Round 3
// 3541.558 us; speedup vs baseline: 2.6187x; 2.6187x over previous
//
#include <hip/hip_runtime.h>
#include <stdint.h>
#include <stddef.h>

// Problem constants (match reference)
#define BB 128
#define SS 128
#define EE 256
#define DD 512
#define KK 16
#define LL 1906   // 1 + 127*15
#define RR 2033   // 1 + 127*16
#define NSTEP 127

// ---------------- JAX threefry2x32 (bit-exact, partitionable) ----------------
static __device__ __forceinline__ uint32_t rotl32(uint32_t v, int r) {
  return (v << r) | (v >> (32 - r));
}

static __device__ __forceinline__ void tf2x32(uint32_t k0, uint32_t k1,
                                              uint32_t x0, uint32_t x1,
                                              uint32_t &o0, uint32_t &o1) {
  uint32_t ks2 = k0 ^ k1 ^ 0x1BD11BDAu;
  x0 += k0; x1 += k1;
#define TFR(r) { x0 += x1; x1 = rotl32(x1, (r)); x1 ^= x0; }
  TFR(13) TFR(15) TFR(26) TFR(6)
  x0 += k1;  x1 += ks2 + 1u;
  TFR(17) TFR(29) TFR(16) TFR(24)
  x0 += ks2; x1 += k0 + 2u;
  TFR(13) TFR(15) TFR(26) TFR(6)
  x0 += k0;  x1 += k1 + 3u;
  TFR(17) TFR(29) TFR(16) TFR(24)
  x0 += k1;  x1 += ks2 + 4u;
  TFR(13) TFR(15) TFR(26) TFR(6)
  x0 += ks2; x1 += k0 + 5u;
#undef TFR
  o0 = x0; o1 = x1;
}

// jax uniform->gumbel for one 32-bit word (minval=f32 tiny, maxval=1)
static __device__ __forceinline__ float jax_gumbel(uint32_t bits) {
  float f = __uint_as_float((bits >> 9) | 0x3F800000u) - 1.0f;
  float u = fmaxf(f, 1.17549435e-38f);
  return -logf(-logf(u));
}

// ---------------- main persistent kernel: one block per batch row ----------------
__global__ __launch_bounds__(1024) void rnn_gen_kernel(
    const int*   __restrict__ marker_data,   // (B,S) int32
    const float* __restrict__ time_data,     // (B,S)
    const float* __restrict__ mask_data,     // (B,S)
    const float* __restrict__ embedding,     // (50000,E)
    const int*   __restrict__ neighbor_list, // (50000,K) int32
    const float* __restrict__ neighbor_prob, // (50000,K)
    const float* __restrict__ W_te,          // (1,E)
    const float* __restrict__ b_te,          // (E)
    const float* __restrict__ W_el,          // (E,D)
    const float* __restrict__ b_el,          // (D)
    const float* __restrict__ W_ih,          // (D,D)
    const float* __restrict__ b_ih,          // (D)
    const float* __restrict__ W_hh,          // (D,D)
    const float* __restrict__ b_hh,          // (D)
    const float* __restrict__ W_time,        // (D,1)
    const float* __restrict__ b_time,        // (1)
    const float* __restrict__ W_mk,          // (E+D,1)
    const float* __restrict__ b_mk,          // (1)
    float* __restrict__ out)                 // 5 x (B,S) f32, concat
{
  __shared__ float  s_prob[LL];
  __shared__ int    s_cand[LL];
  __shared__ float  s_nrec[RR];
  __shared__ float  s_x[DD];
  __shared__ float  s_h[DD];
  __shared__ float  s_vec[EE];
  __shared__ double s_pd[8][DD];     // f64 partial sums (32 KB)
  __shared__ double s_edot[KK];
  __shared__ double s_rt[8];
  __shared__ double s_rm[8];
  __shared__ float  s_red_z[16];
  __shared__ int    s_red_i[16];
  __shared__ int    s_neigh[KK];
  __shared__ float  s_last_t;
  __shared__ int    s_last_m;
  __shared__ int    s_chosen;
  __shared__ float  s_newt;
  __shared__ uint32_t s_k0, s_k1;

  const int b   = blockIdx.x;
  const int tid = threadIdx.x;

  // ---- init carry + col 0 outputs
  for (int i = tid; i < LL; i += 1024) { s_prob[i] = 0.0f; s_cand[i] = 0; }
  for (int i = tid; i < RR; i += 1024) s_nrec[i] = 1.0f;
  if (tid < DD) s_h[tid] = 0.0f;
  if (tid == 0) {
    int   m0 = marker_data[b * SS];
    float t0 = time_data[b * SS];
    s_cand[0] = m0; s_prob[0] = 1.0f;
    s_last_m = m0; s_last_t = t0; s_chosen = 0;
    out[0 * BB * SS + b * SS + 0] = (float)m0;
    out[1 * BB * SS + b * SS + 0] = t0;
    out[2 * BB * SS + b * SS + 0] = mask_data[b * SS];
    out[3 * BB * SS + b * SS + 0] = 1.0f;
    out[4 * BB * SS + b * SS + 0] = 1.0f;
  }
  __syncthreads();

  for (int t = 0; t < NSTEP; ++t) {
    const int   m  = s_last_m;
    const float lt = s_last_t;

    // ---- Phase A: step key, vec, neighbor fetch
    if (tid == 768) {
      uint32_t o0, o1;
      tf2x32(0u, 42u, 0u, (uint32_t)t, o0, o1);
      s_k0 = o0; s_k1 = o1;
    }
    if (tid < EE) {
      float te = __fadd_rn(__fmul_rn(lt, W_te[tid]), b_te[tid]);
      s_vec[tid] = __fadd_rn(embedding[(size_t)m * EE + tid], __fmul_rn(0.1f, te));
    }
    if (tid >= 256 && tid < 256 + KK) {
      int k = tid - 256;
      int nb = neighbor_list[(size_t)m * KK + k];
      s_neigh[k] = nb;
      s_nrec[1 + t * KK + k] = neighbor_prob[(size_t)m * KK + k];
      if (k >= 1) s_cand[1 + t * (KK - 1) + (k - 1)] = nb;
    }
    __syncthreads();  // B1

    // ---- Phase B: W_el partials (all threads) + embedding prefetch (tid>=512)
    float4 ev0 = make_float4(0.f,0.f,0.f,0.f), ev1 = ev0;
    if (tid >= 512) {  // prefetch 16 neighbor embedding rows for the score phase
      int k = (tid - 512) >> 5, l32 = tid & 31;
      const float4* er = (const float4*)(embedding + (size_t)s_neigh[k] * EE);
      ev0 = er[2 * l32]; ev1 = er[2 * l32 + 1];
    }
    {
      const int jg = tid & 127;          // 4 columns 4*jg..4*jg+3
      const int i0 = (tid >> 7) << 5;    // 8 slices of 32 rows
      const float4* W4 = (const float4*)W_el + (size_t)i0 * 128 + jg;
      double d0 = 0.0, d1 = 0.0, d2 = 0.0, d3 = 0.0;
#pragma unroll 4
      for (int i = 0; i < 32; i += 4) {
        float4 a4 = *(const float4*)&s_vec[i0 + i];
        float4 w0 = W4[0], w1 = W4[128], w2 = W4[256], w3 = W4[384];
        W4 += 512;
        d0 = fma((double)a4.x, (double)w0.x, d0); d1 = fma((double)a4.x, (double)w0.y, d1);
        d2 = fma((double)a4.x, (double)w0.z, d2); d3 = fma((double)a4.x, (double)w0.w, d3);
        d0 = fma((double)a4.y, (double)w1.x, d0); d1 = fma((double)a4.y, (double)w1.y, d1);
        d2 = fma((double)a4.y, (double)w1.z, d2); d3 = fma((double)a4.y, (double)w1.w, d3);
        d0 = fma((double)a4.z, (double)w2.x, d0); d1 = fma((double)a4.z, (double)w2.y, d1);
        d2 = fma((double)a4.z, (double)w2.z, d2); d3 = fma((double)a4.z, (double)w2.w, d3);
        d0 = fma((double)a4.w, (double)w3.x, d0); d1 = fma((double)a4.w, (double)w3.y, d1);
        d2 = fma((double)a4.w, (double)w3.z, d2); d3 = fma((double)a4.w, (double)w3.w, d3);
      }
      double* pd = &s_pd[tid >> 7][4 * jg];
      pd[0] = d0; pd[1] = d1; pd[2] = d2; pd[3] = d3;
    }
    __syncthreads();  // B2

    // ---- Phase C: x = leaky((f32)dot + b_el)
    if (tid < DD) {
      double d = ((s_pd[0][tid] + s_pd[1][tid]) + (s_pd[2][tid] + s_pd[3][tid]))
               + ((s_pd[4][tid] + s_pd[5][tid]) + (s_pd[6][tid] + s_pd[7][tid]));
      float z = __fadd_rn((float)d, b_el[tid]);
      s_x[tid] = (z >= 0.0f) ? z : __fmul_rn(0.01f, z);
    }
    __syncthreads();  // B3

    // ---- Phase D: h-matvec partials (tid<512: x@W_ih, tid>=512: h@W_hh)
    {
      const int tl = tid & 511;
      const int jg = tl & 127;
      const int i0 = (tl >> 7) << 7;     // 4 slices of 128 rows
      const float*  av = (tid < 512) ? s_x : s_h;
      const float*  Wm = (tid < 512) ? W_ih : W_hh;
      const float4* W4 = (const float4*)Wm + (size_t)i0 * 128 + jg;
      double d0 = 0.0, d1 = 0.0, d2 = 0.0, d3 = 0.0;
#pragma unroll 4
      for (int i = 0; i < 128; i += 4) {
        float4 a4 = *(const float4*)&av[i0 + i];
        float4 w0 = W4[0], w1 = W4[128], w2 = W4[256], w3 = W4[384];
        W4 += 512;
        d0 = fma((double)a4.x, (double)w0.x, d0); d1 = fma((double)a4.x, (double)w0.y, d1);
        d2 = fma((double)a4.x, (double)w0.z, d2); d3 = fma((double)a4.x, (double)w0.w, d3);
        d0 = fma((double)a4.y, (double)w1.x, d0); d1 = fma((double)a4.y, (double)w1.y, d1);
        d2 = fma((double)a4.y, (double)w1.z, d2); d3 = fma((double)a4.y, (double)w1.w, d3);
        d0 = fma((double)a4.z, (double)w2.x, d0); d1 = fma((double)a4.z, (double)w2.y, d1);
        d2 = fma((double)a4.z, (double)w2.z, d2); d3 = fma((double)a4.z, (double)w2.w, d3);
        d0 = fma((double)a4.w, (double)w3.x, d0); d1 = fma((double)a4.w, (double)w3.y, d1);
        d2 = fma((double)a4.w, (double)w3.z, d2); d3 = fma((double)a4.w, (double)w3.w, d3);
      }
      double* pd = &s_pd[tid >> 7][4 * jg];   // rows 0-3: W_ih slices, 4-7: W_hh
      pd[0] = d0; pd[1] = d1; pd[2] = d2; pd[3] = d3;
    }
    __syncthreads();  // B4

    // ---- Phase E: h = tanh(((x@W_ih + b_ih) + h@W_hh) + b_hh)
    if (tid < DD) {
      double ih = (s_pd[0][tid] + s_pd[1][tid]) + (s_pd[2][tid] + s_pd[3][tid]);
      double hh = (s_pd[4][tid] + s_pd[5][tid]) + (s_pd[6][tid] + s_pd[7][tid]);
      float p = __fadd_rn(__fadd_rn(__fadd_rn((float)ih, b_ih[tid]), (float)hh), b_hh[tid]);
      s_h[tid] = (float)tanh((double)p);
    }
    __syncthreads();  // B5

    // ---- Phase F: tid<512: h.W_time / h.W_mk[E:] wave-reduce; tid>=512: score e-dots
    if (tid < DD) {
      double hv = (double)s_h[tid];
      double pt = hv * (double)W_time[tid];
      double pm = hv * (double)W_mk[EE + tid];
      for (int off = 32; off > 0; off >>= 1) {
        pt += __shfl_down(pt, off);
        pm += __shfl_down(pm, off);
      }
      if ((tid & 63) == 0) { s_rt[tid >> 6] = pt; s_rm[tid >> 6] = pm; }
    } else {
      int k = (tid - 512) >> 5, l32 = tid & 31, e0 = l32 * 8;
      const float4* wm4 = (const float4*)W_mk;
      float4 wm0 = wm4[2 * l32], wm1 = wm4[2 * l32 + 1];
      double acc = 0.0;
      acc = fma((double)ev0.x, (double)wm0.x, acc);
      acc = fma((double)ev0.y, (double)wm0.y, acc);
      acc = fma((double)ev0.z, (double)wm0.z, acc);
      acc = fma((double)ev0.w, (double)wm0.w, acc);
      acc = fma((double)ev1.x, (double)wm1.x, acc);
      acc = fma((double)ev1.y, (double)wm1.y, acc);
      acc = fma((double)ev1.z, (double)wm1.z, acc);
      acc = fma((double)ev1.w, (double)wm1.w, acc);
      (void)e0;
      for (int off = 16; off > 0; off >>= 1) acc += __shfl_down(acc, off, 32);
      if (l32 == 0) s_edot[k] = acc;
    }
    __syncthreads();  // B6

    // ---- Phase G: lanes 0-15: scores+softmax+prob (exact f32 op order); lane 16: new_t
    if (tid < KK) {
      double hmk = ((s_rm[0] + s_rm[1]) + (s_rm[2] + s_rm[3]))
                 + ((s_rm[4] + s_rm[5]) + (s_rm[6] + s_rm[7]));
      float sc = __fadd_rn((float)(s_edot[tid] + hmk), b_mk[0]);
      float mx = sc;
      for (int k = 0; k < KK; ++k) mx = fmaxf(mx, __shfl(sc, k));
      float ee = expf(__fsub_rn(sc, mx));
      float ssum = 0.0f;
      for (int k = 0; k < KK; ++k) ssum = __fadd_rn(ssum, __shfl(ee, k));  // ordered k=0..15
      float cp = s_prob[s_chosen];         // all lanes read BEFORE lane0's write below
      float at = __fmul_rn(cp, __fdiv_rn(ee, ssum));
      if (tid == 0) s_prob[s_chosen] = at;
      else          s_prob[1 + t * (KK - 1) + (tid - 1)] = at;
    } else if (tid == 16) {
      double ht = ((s_rt[0] + s_rt[1]) + (s_rt[2] + s_rt[3]))
                + ((s_rt[4] + s_rt[5]) + (s_rt[6] + s_rt[7]));
      float td = __fadd_rn((float)ht, b_time[0]);
      float sp = __fadd_rn(fmaxf(td, 0.0f), log1pf(expf(-fabsf(td))));
      s_newt = __fadd_rn(s_last_t, sp);
    }
    __syncthreads();  // B7

    // ---- Phase H: categorical sampling (argmax of log prob + gumbel)
    const int active = 16 + 15 * t;
    const uint32_t kk0 = s_k0, kk1 = s_k1;
    float bz = -3.0e38f;
    int   bi = 0x7FFFFFFF;
    for (int l = tid; l < active; l += 1024) {
      uint32_t i = (uint32_t)(b * LL + l);
      uint32_t o0, o1;
      tf2x32(kk0, kk1, 0u, i, o0, o1);
      float g  = jax_gumbel(o0 ^ o1);
      float pr = s_prob[l];
      float z  = (pr > 0.0f) ? __fadd_rn(logf(fmaxf(pr, 1e-38f)), g)
                             : __fadd_rn(-1e30f, g);
      if (z > bz) { bz = z; bi = l; }
    }
    for (int off = 32; off > 0; off >>= 1) {
      float oz = __shfl_down(bz, off);
      int   oi = __shfl_down(bi, off);
      if (oz > bz || (oz == bz && oi < bi)) { bz = oz; bi = oi; }
    }
    if ((tid & 63) == 0) { s_red_z[tid >> 6] = bz; s_red_i[tid >> 6] = bi; }
    __syncthreads();  // B8

    // ---- Phase I: finalize step (thread 0)
    if (tid == 0) {
      float z0 = s_red_z[0]; int i0 = s_red_i[0];
      for (int w = 1; w < 16; ++w) {
        if (s_red_z[w] > z0 || (s_red_z[w] == z0 && s_red_i[w] < i0)) {
          z0 = s_red_z[w]; i0 = s_red_i[w];
        }
      }
      int   nm  = s_cand[i0];
      float np_ = s_nrec[i0];
      float sp_ = s_prob[i0];
      float nt  = s_newt;
      out[0 * BB * SS + b * SS + (t + 1)] = (float)nm;
      out[1 * BB * SS + b * SS + (t + 1)] = nt;
      out[2 * BB * SS + b * SS + (t + 1)] = (nt < 1000.0f) ? 1.0f : 0.0f;
      out[3 * BB * SS + b * SS + (t + 1)] = np_;
      out[4 * BB * SS + b * SS + (t + 1)] = sp_;
      s_chosen = i0; s_last_m = nm; s_last_t = nt;
    }
    __syncthreads();  // B9
  }
}

extern "C" void kernel_launch(void* const* d_in, const int* in_sizes, int n_in,
                              void* d_out, int out_size, void* d_ws, size_t ws_size,
                              hipStream_t stream) {
  (void)in_sizes; (void)n_in; (void)out_size; (void)d_ws; (void)ws_size;
  const int*   marker_data   = (const int*)  d_in[0];
  const float* time_data     = (const float*)d_in[1];
  const float* mask_data     = (const float*)d_in[2];
  const float* embedding     = (const float*)d_in[3];
  const int*   neighbor_list = (const int*)  d_in[4];
  const float* neighbor_prob = (const float*)d_in[5];
  const float* W_te   = (const float*)d_in[6];
  const float* b_te   = (const float*)d_in[7];
  const float* W_el   = (const float*)d_in[8];
  const float* b_el   = (const float*)d_in[9];
  const float* W_ih   = (const float*)d_in[10];
  const float* b_ih   = (const float*)d_in[11];
  const float* W_hh   = (const float*)d_in[12];
  const float* b_hh   = (const float*)d_in[13];
  const float* W_time = (const float*)d_in[14];
  const float* b_time = (const float*)d_in[15];
  const float* W_mk   = (const float*)d_in[16];
  const float* b_mk   = (const float*)d_in[17];
  float* out = (float*)d_out;

  hipLaunchKernelGGL(rnn_gen_kernel, dim3(BB), dim3(1024), 0, stream,
                     marker_data, time_data, mask_data, embedding,
                     neighbor_list, neighbor_prob,
                     W_te, b_te, W_el, b_el, W_ih, b_ih, W_hh, b_hh,
                     W_time, b_time, W_mk, b_mk, out);
}